// Round 1
// baseline (329.514 us; speedup 1.0000x reference)
//
#include <hip/hip_runtime.h>
#include <math.h>

#define B_  2
#define NQ  13294
#define NK  13294
#define DM  256
#define NH  8
#define NL  4
#define NPT 4
#define QB  16

// ---------------- SGEMM: C[M][N] = A[M][K] @ W[K][N] + bias[N] ----------------
#define GBM 64
#define GBN 64
#define GBK 16

__global__ __launch_bounds__(256) void sgemm_bias(
    const float* __restrict__ A, const float* __restrict__ W,
    const float* __restrict__ bias, float* __restrict__ C,
    int M, int N, int K) {
  __shared__ float As[GBK][GBM];  // transposed: As[k][m]
  __shared__ float Bs[GBK][GBN];

  const int t  = threadIdx.x;
  const int bm = blockIdx.x * GBM;
  const int bn = blockIdx.y * GBN;
  const int tm = (t >> 4) * 4;
  const int tn = (t & 15) * 4;

  const int ar  = t >> 2;        // 0..63 (A tile row)
  const int ac  = (t & 3) * 4;   // 0,4,8,12 (A tile k)
  const int bkr = t >> 4;        // 0..15 (B tile k)
  const int bc  = (t & 15) * 4;  // 0..60 (B tile n)

  float acc[4][4];
#pragma unroll
  for (int i = 0; i < 4; ++i)
#pragma unroll
    for (int j = 0; j < 4; ++j) acc[i][j] = 0.f;

  for (int k0 = 0; k0 < K; k0 += GBK) {
    // load A tile (transposed into LDS), guard M edge
    float4 av = make_float4(0.f, 0.f, 0.f, 0.f);
    int arow = bm + ar;
    if (arow < M) av = *(const float4*)&A[(size_t)arow * K + k0 + ac];
    As[ac + 0][ar] = av.x;
    As[ac + 1][ar] = av.y;
    As[ac + 2][ar] = av.z;
    As[ac + 3][ar] = av.w;
    // load B tile
    *(float4*)&Bs[bkr][bc] = *(const float4*)&W[(size_t)(k0 + bkr) * N + bn + bc];
    __syncthreads();
#pragma unroll
    for (int k = 0; k < GBK; ++k) {
      float4 a4 = *(const float4*)&As[k][tm];
      float4 b4 = *(const float4*)&Bs[k][tn];
      acc[0][0] += a4.x * b4.x; acc[0][1] += a4.x * b4.y; acc[0][2] += a4.x * b4.z; acc[0][3] += a4.x * b4.w;
      acc[1][0] += a4.y * b4.x; acc[1][1] += a4.y * b4.y; acc[1][2] += a4.y * b4.z; acc[1][3] += a4.y * b4.w;
      acc[2][0] += a4.z * b4.x; acc[2][1] += a4.z * b4.y; acc[2][2] += a4.z * b4.z; acc[2][3] += a4.z * b4.w;
      acc[3][0] += a4.w * b4.x; acc[3][1] += a4.w * b4.y; acc[3][2] += a4.w * b4.z; acc[3][3] += a4.w * b4.w;
    }
    __syncthreads();
  }

  float4 bias4 = *(const float4*)&bias[bn + tn];
#pragma unroll
  for (int i = 0; i < 4; ++i) {
    int row = bm + tm + i;
    if (row < M) {
      float4 o;
      o.x = acc[i][0] + bias4.x;
      o.y = acc[i][1] + bias4.y;
      o.z = acc[i][2] + bias4.z;
      o.w = acc[i][3] + bias4.w;
      *(float4*)&C[(size_t)row * N + bn + tn] = o;
    }
  }
}

// ------------- fused: sampling params (offsets, softmax weights) + gather -------------
__global__ __launch_bounds__(256) void params_sample(
    const float* __restrict__ query, const float* __restrict__ refp,
    const float* __restrict__ Ws, const float* __restrict__ bs,
    const float* __restrict__ Wa, const float* __restrict__ ba,
    const float* __restrict__ value, float* __restrict__ acc_out) {
  // smem layout (floats):
  //   [0,4096)      qlds  [QB][256]   -- dead after param phase; reused by combo tables
  //   [4096,8192)   offs  [QB][256]
  //   [8192,10240)  attw  [QB][128]
  __shared__ float smem[10240];
  float* qlds = smem;
  float* offs = smem + 4096;
  float* attw = smem + 8192;
  int*   cidx = (int*)smem;       // [512][4] corner indices (aliases qlds)
  float* cw   = smem + 2048;      // [512][4] corner weights (aliases qlds)

  const int t  = threadIdx.x;
  const int q0 = blockIdx.x * QB;
  const int bb = blockIdx.y;
  const int nvalid = min(QB, NQ - q0);

  // ---- P1: stage query rows ----
  for (int i = t; i < QB * 64; i += 256) {  // QB*256/4 float4s
    int qq = i >> 6;
    int c4 = (i & 63) << 2;
    float4 v = make_float4(0.f, 0.f, 0.f, 0.f);
    if (qq < nvalid)
      v = *(const float4*)&query[((size_t)bb * NQ + q0 + qq) * DM + c4];
    *(float4*)&qlds[qq * DM + c4] = v;
  }
  __syncthreads();

  // ---- P2: offsets column t ----
  {
    float oacc[QB];
#pragma unroll
    for (int q = 0; q < QB; ++q) oacc[q] = 0.f;
    for (int k = 0; k < DM; k += 4) {
      float w0 = Ws[(k + 0) * 256 + t];
      float w1 = Ws[(k + 1) * 256 + t];
      float w2 = Ws[(k + 2) * 256 + t];
      float w3 = Ws[(k + 3) * 256 + t];
#pragma unroll
      for (int q = 0; q < QB; ++q) {
        float4 qv = *(const float4*)&qlds[q * DM + k];
        oacc[q] += qv.x * w0 + qv.y * w1 + qv.z * w2 + qv.w * w3;
      }
    }
    float bsv = bs[t];
#pragma unroll
    for (int q = 0; q < QB; ++q) offs[q * DM + t] = oacc[q] + bsv;
  }

  // ---- P2b: attention logits, columns 0..127 ----
  if (t < 128) {
    float lacc[QB];
#pragma unroll
    for (int q = 0; q < QB; ++q) lacc[q] = 0.f;
    for (int k = 0; k < DM; k += 4) {
      float w0 = Wa[(k + 0) * 128 + t];
      float w1 = Wa[(k + 1) * 128 + t];
      float w2 = Wa[(k + 2) * 128 + t];
      float w3 = Wa[(k + 3) * 128 + t];
#pragma unroll
      for (int q = 0; q < QB; ++q) {
        float4 qv = *(const float4*)&qlds[q * DM + k];
        lacc[q] += qv.x * w0 + qv.y * w1 + qv.z * w2 + qv.w * w3;
      }
    }
    float bav = ba[t];
#pragma unroll
    for (int q = 0; q < QB; ++q) attw[q * 128 + t] = lacc[q] + bav;
  }
  __syncthreads();

  // ---- P3: softmax over 16 (level,point) per (q,head) ----
  if (t < 128) {
    int ql = t >> 3, h = t & 7;
    float* aw = &attw[ql * 128 + h * 16];
    float m = aw[0];
#pragma unroll
    for (int j = 1; j < 16; ++j) m = fmaxf(m, aw[j]);
    float e[16], s = 0.f;
#pragma unroll
    for (int j = 0; j < 16; ++j) { e[j] = expf(aw[j] - m); s += e[j]; }
    float inv = 1.f / s;
#pragma unroll
    for (int j = 0; j < 16; ++j) aw[j] = e[j] * inv;
  }

  // ---- P4: per 4-query chunk: combo tables then gather ----
  const int LW[4]     = {100, 50, 25, 13};
  const int LSTART[4] = {0, 10000, 12500, 13125};
  const int h  = t >> 5;
  const int ch = t & 31;
  const float* vbase = value + (size_t)bb * NK * DM + t;  // t == h*32+ch

  for (int qc = 0; qc < QB; qc += 4) {
    __syncthreads();  // attw/offs ready (first iter); previous gather done (later iters)
    for (int i = t; i < 4 * 128; i += 256) {
      int ql  = qc + (i >> 7);
      int rem = i & 127;            // h*16 + l*4 + p
      int l   = (rem >> 2) & 3;
      bool valid = ql < nvalid;
      float wa = valid ? attw[ql * 128 + rem] : 0.f;
      float offx = offs[ql * DM + rem * 2 + 0];
      float offy = offs[ql * DM + rem * 2 + 1];
      float rx = 0.f, ry = 0.f;
      if (valid) {
        const float* rp = refp + (((size_t)bb * NQ + q0 + ql) * NL + l) * 2;
        rx = rp[0];
        ry = rp[1];
      }
      float dimf = (float)LW[l];
      // NOTE: module divides (x,y) by (H,W); H==W at every level here.
      float locx = rx + offx / dimf;
      float locy = ry + offy / dimf;
      float gx = 2.f * locx - 1.f;
      float gy = 2.f * locy - 1.f;
      float x = (gx + 1.f) * (dimf * 0.5f) - 0.5f;
      float y = (gy + 1.f) * (dimf * 0.5f) - 0.5f;
      float xf = floorf(x), yf = floorf(y);
      float dx = x - xf, dy = y - yf;
      int x0 = (int)xf, y0 = (int)yf;
      int Wd = LW[l];
      float w00 = (1.f - dx) * (1.f - dy) * wa;
      float w10 = dx * (1.f - dy) * wa;
      float w01 = (1.f - dx) * dy * wa;
      float w11 = dx * dy * wa;
      int base = LSTART[l];

      int xi, yi;
      int i0, i1, i2, i3;
      xi = x0;     yi = y0;
      if (valid && xi >= 0 && xi < Wd && yi >= 0 && yi < Wd) i0 = base + yi * Wd + xi; else { i0 = 0; w00 = 0.f; }
      xi = x0 + 1; yi = y0;
      if (valid && xi >= 0 && xi < Wd && yi >= 0 && yi < Wd) i1 = base + yi * Wd + xi; else { i1 = 0; w10 = 0.f; }
      xi = x0;     yi = y0 + 1;
      if (valid && xi >= 0 && xi < Wd && yi >= 0 && yi < Wd) i2 = base + yi * Wd + xi; else { i2 = 0; w01 = 0.f; }
      xi = x0 + 1; yi = y0 + 1;
      if (valid && xi >= 0 && xi < Wd && yi >= 0 && yi < Wd) i3 = base + yi * Wd + xi; else { i3 = 0; w11 = 0.f; }

      cidx[i * 4 + 0] = i0; cw[i * 4 + 0] = w00;
      cidx[i * 4 + 1] = i1; cw[i * 4 + 1] = w10;
      cidx[i * 4 + 2] = i2; cw[i * 4 + 2] = w01;
      cidx[i * 4 + 3] = i3; cw[i * 4 + 3] = w11;
    }
    __syncthreads();

    // gather: thread (h,ch); lanes of a head read 128B contiguous
#pragma unroll
    for (int qi = 0; qi < 4; ++qi) {
      int ql = qc + qi;
      int cbase = (qi << 7) + (h << 4);
      float a = 0.f;
#pragma unroll
      for (int lp = 0; lp < 16; ++lp) {
        int ci = (cbase + lp) << 2;
        int i0 = cidx[ci + 0], i1 = cidx[ci + 1], i2 = cidx[ci + 2], i3 = cidx[ci + 3];
        float w0 = cw[ci + 0], w1 = cw[ci + 1], w2 = cw[ci + 2], w3 = cw[ci + 3];
        a += w0 * vbase[(size_t)i0 * DM];
        a += w1 * vbase[(size_t)i1 * DM];
        a += w2 * vbase[(size_t)i2 * DM];
        a += w3 * vbase[(size_t)i3 * DM];
      }
      if (ql < nvalid)
        acc_out[((size_t)bb * NQ + q0 + ql) * DM + t] = a;
    }
  }
}

extern "C" void kernel_launch(void* const* d_in, const int* in_sizes, int n_in,
                              void* d_out, int out_size, void* d_ws, size_t ws_size,
                              hipStream_t stream) {
  const float* query = (const float*)d_in[0];
  const float* refp  = (const float*)d_in[1];
  const float* inpf  = (const float*)d_in[2];
  const float* Wv    = (const float*)d_in[3];
  const float* bv    = (const float*)d_in[4];
  const float* Ws    = (const float*)d_in[5];
  const float* bs    = (const float*)d_in[6];
  const float* Wa    = (const float*)d_in[7];
  const float* ba    = (const float*)d_in[8];
  const float* Wo    = (const float*)d_in[9];
  const float* bo    = (const float*)d_in[10];
  float* out = (float*)d_out;

  float* value = (float*)d_ws;                       // (B, NK, 256)
  float* acc   = value + (size_t)B_ * NK * DM;       // (B, NQ, 256)

  const int M = B_ * NK;
  dim3 gemm_grid((M + GBM - 1) / GBM, DM / GBN);

  sgemm_bias<<<gemm_grid, 256, 0, stream>>>(inpf, Wv, bv, value, M, DM, DM);

  dim3 samp_grid((NQ + QB - 1) / QB, B_);
  params_sample<<<samp_grid, 256, 0, stream>>>(query, refp, Ws, bs, Wa, ba, value, acc);

  sgemm_bias<<<gemm_grid, 256, 0, stream>>>(acc, Wo, bo, out, M, DM, DM);
}

// Round 2
// 309.710 us; speedup vs baseline: 1.0639x; 1.0639x over previous
//
#include <hip/hip_runtime.h>
#include <math.h>

#define B_  2
#define NQ  13294
#define NK  13294
#define DM  256
#define NH  8
#define QB  16

// ---------------- SGEMM: C[M][N] = A[M][K] @ W[K][N] + bias[N] ----------------
#define GBM 64
#define GBN 64
#define GBK 16

__global__ __launch_bounds__(256) void sgemm_bias(
    const float* __restrict__ A, const float* __restrict__ W,
    const float* __restrict__ bias, float* __restrict__ C,
    int M, int N, int K) {
  __shared__ float As[GBK][GBM];  // transposed: As[k][m]
  __shared__ float Bs[GBK][GBN];

  const int t  = threadIdx.x;
  const int bm = blockIdx.x * GBM;
  const int bn = blockIdx.y * GBN;
  const int tm = (t >> 4) * 4;
  const int tn = (t & 15) * 4;

  const int ar  = t >> 2;        // 0..63 (A tile row)
  const int ac  = (t & 3) * 4;   // 0,4,8,12 (A tile k)
  const int bkr = t >> 4;        // 0..15 (B tile k)
  const int bc  = (t & 15) * 4;  // 0..60 (B tile n)

  float acc[4][4];
#pragma unroll
  for (int i = 0; i < 4; ++i)
#pragma unroll
    for (int j = 0; j < 4; ++j) acc[i][j] = 0.f;

  for (int k0 = 0; k0 < K; k0 += GBK) {
    float4 av = make_float4(0.f, 0.f, 0.f, 0.f);
    int arow = bm + ar;
    if (arow < M) av = *(const float4*)&A[(size_t)arow * K + k0 + ac];
    As[ac + 0][ar] = av.x;
    As[ac + 1][ar] = av.y;
    As[ac + 2][ar] = av.z;
    As[ac + 3][ar] = av.w;
    *(float4*)&Bs[bkr][bc] = *(const float4*)&W[(size_t)(k0 + bkr) * N + bn + bc];
    __syncthreads();
#pragma unroll
    for (int k = 0; k < GBK; ++k) {
      float4 a4 = *(const float4*)&As[k][tm];
      float4 b4 = *(const float4*)&Bs[k][tn];
      acc[0][0] += a4.x * b4.x; acc[0][1] += a4.x * b4.y; acc[0][2] += a4.x * b4.z; acc[0][3] += a4.x * b4.w;
      acc[1][0] += a4.y * b4.x; acc[1][1] += a4.y * b4.y; acc[1][2] += a4.y * b4.z; acc[1][3] += a4.y * b4.w;
      acc[2][0] += a4.z * b4.x; acc[2][1] += a4.z * b4.y; acc[2][2] += a4.z * b4.z; acc[2][3] += a4.z * b4.w;
      acc[3][0] += a4.w * b4.x; acc[3][1] += a4.w * b4.y; acc[3][2] += a4.w * b4.z; acc[3][3] += a4.w * b4.w;
    }
    __syncthreads();
  }

  float4 bias4 = *(const float4*)&bias[bn + tn];
#pragma unroll
  for (int i = 0; i < 4; ++i) {
    int row = bm + tm + i;
    if (row < M) {
      float4 o;
      o.x = acc[i][0] + bias4.x;
      o.y = acc[i][1] + bias4.y;
      o.z = acc[i][2] + bias4.z;
      o.w = acc[i][3] + bias4.w;
      *(float4*)&C[(size_t)row * N + bn + tn] = o;
    }
  }
}

// ------------- sampler: softmax + bilinear combo tables + float4 gather -------------
// block = 256 threads, handles QB=16 queries of one batch, in chunks of 4.
// gather: lane = h*8 + c4 ; one wave covers all 8 heads x 32 channels for one query.
#define PADH 258  // 4q*16lp*4c = 256 combo pairs per head, +2 pad -> bank spread

__global__ __launch_bounds__(256) void sampler(
    const float* __restrict__ refp, const float* __restrict__ offs_g,
    const float* __restrict__ logit_g, const float* __restrict__ value,
    float* __restrict__ acc_out) {
  __shared__ float2 combo[NH * PADH];  // {idx-as-float-bits, weight}

  const int t    = threadIdx.x;
  const int q0   = blockIdx.x * QB;
  const int bb   = blockIdx.y;
  const int wid  = t >> 6;       // wave id -> query-in-chunk for gather
  const int lane = t & 63;
  const int h_g  = lane >> 3;    // head for gather
  const int c4   = lane & 7;     // float4 chunk within head
  const float* vbase = value + (size_t)bb * NK * DM + h_g * 32 + c4 * 4;

  const float DIMF[4] = {100.f, 50.f, 25.f, 13.f};
  const int LSTART[4] = {0, 10000, 12500, 13125};

  for (int qc = 0; qc < QB; qc += 4) {
    __syncthreads();  // previous chunk's gather done; combo reusable

    // ---- combo build (threads 0..127): one thread per (q, head, level) ----
    if (t < 128) {
      const int qi = t >> 5;
      const int h  = (t >> 2) & 7;
      const int l  = t & 3;
      const int q  = q0 + qc + qi;
      const bool valid = q < NQ;
      const size_t row = (size_t)bb * NQ + (valid ? q : 0);

      // softmax over this (q,h)'s 16 logits
      const float* lg = &logit_g[row * 128 + h * 16];
      float e[16];
      float m = lg[0];
#pragma unroll
      for (int j = 1; j < 16; ++j) m = fmaxf(m, lg[j]);
      float s = 0.f;
#pragma unroll
      for (int j = 0; j < 16; ++j) { e[j] = __expf(lg[j] - m); s += e[j]; }
      const float inv = 1.f / s;

      const float* rp = &refp[(row * 4 + l) * 2];
      const float rx = rp[0], ry = rp[1];
      const float dimf = DIMF[l];
      const int   Wd   = (int)dimf;
      const int   base = LSTART[l];
      const float* of  = &offs_g[row * 256 + h * 32 + l * 8];
      float2* cb = &combo[h * PADH + qi * 64 + l * 16];

#pragma unroll
      for (int p = 0; p < 4; ++p) {
        const float wa = valid ? e[l * 4 + p] * inv : 0.f;
        // loc = ref + off/dim ; x = loc*dim - 0.5  ->  x = ref*dim + off - 0.5
        const float x = rx * dimf + of[p * 2 + 0] - 0.5f;
        const float y = ry * dimf + of[p * 2 + 1] - 0.5f;
        const float xf = floorf(x), yf = floorf(y);
        const float dx = x - xf, dy = y - yf;
        const int x0 = (int)xf, y0 = (int)yf;
        float w00 = (1.f - dx) * (1.f - dy) * wa;
        float w10 = dx * (1.f - dy) * wa;
        float w01 = (1.f - dx) * dy * wa;
        float w11 = dx * dy * wa;
        int i0, i1, i2, i3, xi, yi;
        xi = x0;     yi = y0;
        if (xi >= 0 && xi < Wd && yi >= 0 && yi < Wd) i0 = base + yi * Wd + xi; else { i0 = 0; w00 = 0.f; }
        xi = x0 + 1; yi = y0;
        if (xi >= 0 && xi < Wd && yi >= 0 && yi < Wd) i1 = base + yi * Wd + xi; else { i1 = 0; w10 = 0.f; }
        xi = x0;     yi = y0 + 1;
        if (xi >= 0 && xi < Wd && yi >= 0 && yi < Wd) i2 = base + yi * Wd + xi; else { i2 = 0; w01 = 0.f; }
        xi = x0 + 1; yi = y0 + 1;
        if (xi >= 0 && xi < Wd && yi >= 0 && yi < Wd) i3 = base + yi * Wd + xi; else { i3 = 0; w11 = 0.f; }
        cb[p * 4 + 0] = make_float2(__int_as_float(i0), w00);
        cb[p * 4 + 1] = make_float2(__int_as_float(i1), w10);
        cb[p * 4 + 2] = make_float2(__int_as_float(i2), w01);
        cb[p * 4 + 3] = make_float2(__int_as_float(i3), w11);
      }
    }
    __syncthreads();

    // ---- gather: wave `wid` handles query qc+wid, all heads at once ----
    {
      const int q = q0 + qc + wid;
      const float2* cb = &combo[h_g * PADH + wid * 64];
      float4 a = make_float4(0.f, 0.f, 0.f, 0.f);
#pragma unroll 8
      for (int j = 0; j < 64; ++j) {
        const float2 e = cb[j];
        const int idx = __float_as_int(e.x);
        const float w = e.y;
        const float4 v = *(const float4*)(vbase + ((size_t)idx << 8));
        a.x += w * v.x; a.y += w * v.y; a.z += w * v.z; a.w += w * v.w;
      }
      if (q < NQ)
        *(float4*)&acc_out[((size_t)bb * NQ + q) * DM + lane * 4] = a;
    }
  }
}

extern "C" void kernel_launch(void* const* d_in, const int* in_sizes, int n_in,
                              void* d_out, int out_size, void* d_ws, size_t ws_size,
                              hipStream_t stream) {
  const float* query = (const float*)d_in[0];
  const float* refp  = (const float*)d_in[1];
  const float* inpf  = (const float*)d_in[2];
  const float* Wv    = (const float*)d_in[3];
  const float* bv    = (const float*)d_in[4];
  const float* Ws    = (const float*)d_in[5];
  const float* bs    = (const float*)d_in[6];
  const float* Wa    = (const float*)d_in[7];
  const float* ba    = (const float*)d_in[8];
  const float* Wo    = (const float*)d_in[9];
  const float* bo    = (const float*)d_in[10];
  float* out = (float*)d_out;

  float* value   = (float*)d_ws;                        // (B*NK, 256)  27.2 MB
  float* acc     = value   + (size_t)B_ * NK * DM;      // (B*NQ, 256)  27.2 MB
  float* offs_g  = acc     + (size_t)B_ * NQ * DM;      // (B*NQ, 256)  27.2 MB
  float* logit_g = offs_g  + (size_t)B_ * NQ * DM;      // (B*NQ, 128)  13.6 MB

  const int M = B_ * NK;
  dim3 g256((M + GBM - 1) / GBM, 256 / GBN);
  dim3 g128((M + GBM - 1) / GBM, 128 / GBN);

  sgemm_bias<<<g256, 256, 0, stream>>>(inpf,  Wv, bv, value,   M, 256, 256);
  sgemm_bias<<<g256, 256, 0, stream>>>(query, Ws, bs, offs_g,  M, 256, 256);
  sgemm_bias<<<g128, 256, 0, stream>>>(query, Wa, ba, logit_g, M, 128, 256);

  dim3 samp_grid((NQ + QB - 1) / QB, B_);
  sampler<<<samp_grid, 256, 0, stream>>>(refp, offs_g, logit_g, value, acc);

  sgemm_bias<<<g256, 256, 0, stream>>>(acc, Wo, bo, out, M, 256, 256);
}

// Round 4
// 148.874 us; speedup vs baseline: 2.2134x; 2.0804x over previous
//
#include <hip/hip_runtime.h>
#include <hip/hip_bf16.h>
#include <math.h>

#define B_  2
#define NQ  13294
#define NK  13294

typedef __bf16 bf16x8 __attribute__((ext_vector_type(8)));
typedef float f32x4 __attribute__((ext_vector_type(4)));

static __device__ __forceinline__ f32x4 mfma16(bf16x8 a, bf16x8 b, f32x4 c) {
  return __builtin_amdgcn_mfma_f32_16x16x32_bf16(a, b, c, 0, 0, 0);
}

// ---- pack weights f32 [K=256][N] -> bf16 MFMA B-fragment layout ----
// layout: [bn][kt][n_sub][lane][j], n = bn*64 + n_sub*16 + (lane&15),
//         k = kt*32 + (lane>>4)*8 + j
__global__ __launch_bounds__(256) void pack_w(
    const float* __restrict__ W1, const float* __restrict__ W2,
    int N1, int Ntot, __hip_bfloat16* __restrict__ out) {
  int g = blockIdx.x * 256 + threadIdx.x;
  int total = (Ntot >> 6) * 2048;
  if (g >= total) return;
  int lane = g & 63;
  int n_sub = (g >> 6) & 3;
  int kt = (g >> 8) & 7;
  int bn = g >> 11;
  int n = bn * 64 + n_sub * 16 + (lane & 15);
  int k0 = kt * 32 + (lane >> 4) * 8;
  const float* src; int nn, Ns;
  if (n < N1) { src = W1; nn = n; Ns = N1; }
  else        { src = W2; nn = n - N1; Ns = Ntot - N1; }
  bf16x8 v;
#pragma unroll
  for (int j = 0; j < 8; ++j) v[j] = (__bf16)src[(size_t)(k0 + j) * Ns + nn];
  *(bf16x8*)((__hip_bfloat16*)out + (size_t)g * 8) = v;
}

// ---- MFMA GEMM: C[M][N] = A[M][256] @ Wpack + bias ; BM=64, BN=64 per nb ----
template<bool ABF16, bool CBF16>
__global__ __launch_bounds__(256) void gemm_mfma(
    const void* __restrict__ Ain, const __hip_bfloat16* __restrict__ Bpack,
    const float* __restrict__ b1, const float* __restrict__ b2, int N1,
    void* __restrict__ Cout, int M, int N) {
  __shared__ bf16x8 As[8 * 4 * 64];   // [kt][sm][lane]  32 KB
  __shared__ bf16x8 Bs[8 * 4 * 64];   // [kt][n_sub][lane] 32 KB

  const int t = threadIdx.x;
  const int bm = blockIdx.x * 64;
  const int lane = t & 63;
  const int wid = t >> 6;
  const int wm = wid >> 1, wn = wid & 1;

  // stage A once (all K=256), fragment order
  {
    const int r = t >> 2;           // 0..63
    const int row = bm + r;
    const int sm = r >> 4;
    const int lb = r & 15;
    const bool ok = row < M;
    if (!ABF16) {
      const float* ap = (const float*)Ain + (size_t)row * 256 + (t & 3) * 64;
#pragma unroll
      for (int gi = 0; gi < 8; ++gi) {
        float4 u = make_float4(0.f,0.f,0.f,0.f), v = make_float4(0.f,0.f,0.f,0.f);
        if (ok) { u = *(const float4*)(ap + gi * 8); v = *(const float4*)(ap + gi * 8 + 4); }
        bf16x8 w;
        w[0]=(__bf16)u.x; w[1]=(__bf16)u.y; w[2]=(__bf16)u.z; w[3]=(__bf16)u.w;
        w[4]=(__bf16)v.x; w[5]=(__bf16)v.y; w[6]=(__bf16)v.z; w[7]=(__bf16)v.w;
        int k8 = (t & 3) * 8 + gi;
        As[((k8 >> 2) * 4 + sm) * 64 + lb + ((k8 & 3) << 4)] = w;
      }
    } else {
      const __hip_bfloat16* ap = (const __hip_bfloat16*)Ain + (size_t)row * 256 + (t & 3) * 64;
#pragma unroll
      for (int gi = 0; gi < 8; ++gi) {
        bf16x8 w = {};
        if (ok) w = *(const bf16x8*)(ap + gi * 8);
        int k8 = (t & 3) * 8 + gi;
        As[((k8 >> 2) * 4 + sm) * 64 + lb + ((k8 & 3) << 4)] = w;
      }
    }
  }

  const int NB = N >> 6;
  for (int nb = 0; nb < NB; ++nb) {
    __syncthreads();   // As ready (first iter) / previous compute done reading Bs
    {
      const bf16x8* bp = (const bf16x8*)Bpack + (size_t)nb * 2048;
#pragma unroll
      for (int it = 0; it < 8; ++it) Bs[it * 256 + t] = bp[it * 256 + t];
    }
    __syncthreads();

    f32x4 acc[2][2] = {};
#pragma unroll
    for (int kt = 0; kt < 8; ++kt) {
      bf16x8 a0 = As[(kt * 4 + wm * 2 + 0) * 64 + lane];
      bf16x8 a1 = As[(kt * 4 + wm * 2 + 1) * 64 + lane];
      bf16x8 q0 = Bs[(kt * 4 + wn * 2 + 0) * 64 + lane];
      bf16x8 q1 = Bs[(kt * 4 + wn * 2 + 1) * 64 + lane];
      acc[0][0] = mfma16(a0, q0, acc[0][0]);
      acc[0][1] = mfma16(a0, q1, acc[0][1]);
      acc[1][0] = mfma16(a1, q0, acc[1][0]);
      acc[1][1] = mfma16(a1, q1, acc[1][1]);
    }

#pragma unroll
    for (int n = 0; n < 2; ++n) {
      const int col = nb * 64 + wn * 32 + n * 16 + (lane & 15);
      const float bias = (col < N1) ? b1[col] : b2[col - N1];
#pragma unroll
      for (int m = 0; m < 2; ++m) {
        const int rbase = bm + wm * 32 + m * 16 + (lane >> 4) * 4;
#pragma unroll
        for (int rg = 0; rg < 4; ++rg) {
          const int row = rbase + rg;
          if (row < M) {
            const float v = acc[m][n][rg] + bias;
            if (CBF16) ((__hip_bfloat16*)Cout)[(size_t)row * N + col] = (__hip_bfloat16)(__bf16)v;
            else       ((float*)Cout)[(size_t)row * N + col] = v;
          }
        }
      }
    }
  }
}

// ---- sampler: softmax + bilinear combos + bf16 gather ----
// 16 queries/block, chunks of 8; wave covers 2 queries x 8 heads x 4 chunks-of-8ch.
// combo layout: [(q*8 + h)*CS + e], e = l*16 + p*4 + corner  (flat 0..63).
// CS = 65 (odd) -> the 16 distinct (q2,head) addresses per gather instruction are
// 16 consecutive ints * odd stride -> distinct mod 16 -> conflict-free ds_read_b64.
#define CS 65

__global__ __launch_bounds__(256) void sampler(
    const float* __restrict__ refp, const float* __restrict__ params,
    const __hip_bfloat16* __restrict__ value, __hip_bfloat16* __restrict__ acc_out) {
  __shared__ float2 combo[64 * CS];  // 33.3 KB

  const int t = threadIdx.x;
  const int q0 = blockIdx.x * 16;
  const int bb = blockIdx.y;

  const int cqi = t >> 5;          // build: query 0..7
  const int chh = (t >> 2) & 7;    // build: head
  const int cl  = t & 3;           // build: level

  const int lane = t & 63;
  const int wid  = t >> 6;
  const int q2   = lane >> 5;
  const int gh   = (lane >> 2) & 7;
  const int gs   = lane & 3;
  const char* vbase = (const char*)value + ((size_t)bb * NK * 256 + gh * 32 + gs * 8) * 2;

  const float DIMF[4]  = {100.f, 50.f, 25.f, 13.f};
  const int   LSTART[4] = {0, 10000, 12500, 13125};
  const float dimf  = DIMF[cl];
  const int   Wd    = (int)dimf;
  const int   lbase = LSTART[cl];

  for (int qc = 0; qc < 16; qc += 8) {
    __syncthreads();  // previous chunk's gather done
    // ---- build combo tables: one thread per (q, head, level) ----
    {
      const int q = q0 + qc + cqi;
      const bool valid = q < NQ;
      const size_t row = (size_t)bb * NQ + (valid ? q : 0);
      const float* pr = params + row * 384;
      const float* lg = pr + 256 + chh * 16;
      float m = lg[0];
#pragma unroll
      for (int j = 1; j < 16; ++j) m = fmaxf(m, lg[j]);
      float s = 0.f;
#pragma unroll
      for (int j = 0; j < 16; ++j) s += __expf(lg[j] - m);
      const float inv = valid ? 1.f / s : 0.f;

      const float rx = refp[(row * 4 + cl) * 2 + 0];
      const float ry = refp[(row * 4 + cl) * 2 + 1];
      const float* of = pr + chh * 32 + cl * 8;
      float2* cb = &combo[(cqi * 8 + chh) * CS + cl * 16];

#pragma unroll
      for (int p = 0; p < 4; ++p) {
        const float wa = __expf(lg[cl * 4 + p] - m) * inv;
        const float x = rx * dimf + of[p * 2 + 0] - 0.5f;
        const float y = ry * dimf + of[p * 2 + 1] - 0.5f;
        const float xf = floorf(x), yf = floorf(y);
        const float dx = x - xf, dy = y - yf;
        const int x0 = (int)xf, y0 = (int)yf;
        float w00 = (1.f - dx) * (1.f - dy) * wa;
        float w10 = dx * (1.f - dy) * wa;
        float w01 = (1.f - dx) * dy * wa;
        float w11 = dx * dy * wa;
        int i0, i1, i2, i3, xi, yi;
        xi = x0;     yi = y0;
        if (xi >= 0 && xi < Wd && yi >= 0 && yi < Wd) i0 = lbase + yi * Wd + xi; else { i0 = 0; w00 = 0.f; }
        xi = x0 + 1; yi = y0;
        if (xi >= 0 && xi < Wd && yi >= 0 && yi < Wd) i1 = lbase + yi * Wd + xi; else { i1 = 0; w10 = 0.f; }
        xi = x0;     yi = y0 + 1;
        if (xi >= 0 && xi < Wd && yi >= 0 && yi < Wd) i2 = lbase + yi * Wd + xi; else { i2 = 0; w01 = 0.f; }
        xi = x0 + 1; yi = y0 + 1;
        if (xi >= 0 && xi < Wd && yi >= 0 && yi < Wd) i3 = lbase + yi * Wd + xi; else { i3 = 0; w11 = 0.f; }
        cb[p * 4 + 0] = make_float2(__int_as_float(i0), w00);
        cb[p * 4 + 1] = make_float2(__int_as_float(i1), w10);
        cb[p * 4 + 2] = make_float2(__int_as_float(i2), w01);
        cb[p * 4 + 3] = make_float2(__int_as_float(i3), w11);
      }
    }
    __syncthreads();

    // ---- gather: wave wid covers queries {2*wid, 2*wid+1} of the chunk ----
    {
      const int qw = wid * 2 + q2;
      const int q = q0 + qc + qw;
      const float2* cb = &combo[(qw * 8 + gh) * CS];
      float a0=0.f,a1=0.f,a2=0.f,a3=0.f,a4=0.f,a5=0.f,a6=0.f,a7=0.f;
#pragma unroll 8
      for (int e = 0; e < 64; ++e) {
        const float2 en = cb[e];
        const int idx = __float_as_int(en.x);
        const float w = en.y;
        const uint4 v = *(const uint4*)(vbase + ((size_t)idx << 9));
        a0 += w * __uint_as_float(v.x << 16);
        a1 += w * __uint_as_float(v.x & 0xffff0000u);
        a2 += w * __uint_as_float(v.y << 16);
        a3 += w * __uint_as_float(v.y & 0xffff0000u);
        a4 += w * __uint_as_float(v.z << 16);
        a5 += w * __uint_as_float(v.z & 0xffff0000u);
        a6 += w * __uint_as_float(v.w << 16);
        a7 += w * __uint_as_float(v.w & 0xffff0000u);
      }
      if (q < NQ) {
        bf16x8 o;
        o[0]=(__bf16)a0; o[1]=(__bf16)a1; o[2]=(__bf16)a2; o[3]=(__bf16)a3;
        o[4]=(__bf16)a4; o[5]=(__bf16)a5; o[6]=(__bf16)a6; o[7]=(__bf16)a7;
        *(bf16x8*)((char*)acc_out + (((size_t)bb * NQ + q) * 256 + gh * 32 + gs * 8) * 2) = o;
      }
    }
  }
}

extern "C" void kernel_launch(void* const* d_in, const int* in_sizes, int n_in,
                              void* d_out, int out_size, void* d_ws, size_t ws_size,
                              hipStream_t stream) {
  const float* query = (const float*)d_in[0];
  const float* refp  = (const float*)d_in[1];
  const float* inpf  = (const float*)d_in[2];
  const float* Wv    = (const float*)d_in[3];
  const float* bv    = (const float*)d_in[4];
  const float* Ws    = (const float*)d_in[5];
  const float* bs    = (const float*)d_in[6];
  const float* Wa    = (const float*)d_in[7];
  const float* ba    = (const float*)d_in[8];
  const float* Wo    = (const float*)d_in[9];
  const float* bo    = (const float*)d_in[10];
  float* out = (float*)d_out;

  const size_t M = (size_t)B_ * NK;  // 26588
  char* w = (char*)d_ws;
  __hip_bfloat16* value  = (__hip_bfloat16*)w;            w += M * 256 * 2;
  __hip_bfloat16* acc    = (__hip_bfloat16*)w;            w += M * 256 * 2;
  float*          params = (float*)w;                     w += M * 384 * 4;
  __hip_bfloat16* wv_p   = (__hip_bfloat16*)w;            w += 256 * 256 * 2;
  __hip_bfloat16* wsa_p  = (__hip_bfloat16*)w;            w += 256 * 384 * 2;
  __hip_bfloat16* wo_p   = (__hip_bfloat16*)w;

  pack_w<<<32, 256, 0, stream>>>(Wv, Wv, 256, 256, wv_p);
  pack_w<<<48, 256, 0, stream>>>(Ws, Wa, 256, 384, wsa_p);
  pack_w<<<32, 256, 0, stream>>>(Wo, Wo, 256, 256, wo_p);

  const int gx = (int)((M + 63) / 64);  // 416
  gemm_mfma<false, true ><<<gx, 256, 0, stream>>>(inpf,  wv_p,  bv, bv, 256, value,  (int)M, 256);
  gemm_mfma<false, false><<<gx, 256, 0, stream>>>(query, wsa_p, bs, ba, 256, params, (int)M, 384);

  dim3 sgrid((NQ + 15) / 16, B_);
  sampler<<<sgrid, 256, 0, stream>>>(refp, params, value, acc);

  gemm_mfma<true, false><<<gx, 256, 0, stream>>>(acc, wo_p, bo, bo, 256, out, (int)M, 256);
}